// Round 1
// baseline (2640.240 us; speedup 1.0000x reference)
//
#include <hip/hip_runtime.h>

#define FD 64  // feature dim

static __global__ void zero_kernel(float* __restrict__ p, long long n) {
    long long i = (long long)blockIdx.x * blockDim.x + threadIdx.x;
    if (i < n) p[i] = 0.0f;
}

static __global__ void init_concat_kernel(const float* __restrict__ a, long long an,
                                          const float* __restrict__ b, long long bn,
                                          float* __restrict__ cur, float* __restrict__ acc) {
    long long i = (long long)blockIdx.x * blockDim.x + threadIdx.x;
    if (i >= an + bn) return;
    float v = (i < an) ? a[i] : b[i - an];
    cur[i] = v;
    acc[i] = v;
}

// One 64-lane wave per edge; lane d handles feature dim d.
// out[r*64+d] += scale * vals[e] * feats[c*64+d]
static __global__ void spmm_scatter_kernel(const int* __restrict__ rows,
                                           const int* __restrict__ cols,
                                           const float* __restrict__ vals,
                                           const float* __restrict__ feats,
                                           float* __restrict__ out,
                                           int nnz, float scale) {
    long long t = (long long)blockIdx.x * blockDim.x + threadIdx.x;
    int e = (int)(t >> 6);
    if (e >= nnz) return;
    int d = (int)(t & 63);
    int r = rows[e];
    int c = cols[e];
    float v = vals[e] * scale;
    atomicAdd(out + (long long)r * FD + d, v * feats[(long long)c * FD + d]);
}

// One wave per row: acc[r] += feats[r] / max(||feats[r]||_2, 1e-12)
static __global__ void l2norm_acc_kernel(const float* __restrict__ feats,
                                         float* __restrict__ acc, int n) {
    long long t = (long long)blockIdx.x * blockDim.x + threadIdx.x;
    int r = (int)(t >> 6);
    if (r >= n) return;
    int d = (int)(t & 63);
    long long idx = (long long)r * FD + d;
    float v = feats[idx];
    float s = v * v;
    #pragma unroll
    for (int off = 32; off > 0; off >>= 1) s += __shfl_xor(s, off);
    acc[idx] += v / fmaxf(sqrtf(s), 1e-12f);
}

static __global__ void copy_kernel(const float* __restrict__ src, float* __restrict__ dst,
                                   long long n) {
    long long i = (long long)blockIdx.x * blockDim.x + threadIdx.x;
    if (i < n) dst[i] = src[i];
}

static inline unsigned gridFor(long long n, int block) {
    return (unsigned)((n + block - 1) / block);
}

extern "C" void kernel_launch(void* const* d_in, const int* in_sizes, int n_in,
                              void* d_out, int out_size, void* d_ws, size_t ws_size,
                              hipStream_t stream) {
    const float* users   = (const float*)d_in[0];
    const float* items   = (const float*)d_in[1];
    const float* bundles = (const float*)d_in[2];
    const int*   aff_rows = (const int*)d_in[3];
    const int*   aff_cols = (const int*)d_in[4];
    const float* aff_vals = (const float*)d_in[5];
    const int*   hist_rows = (const int*)d_in[6];
    const int*   hist_cols = (const int*)d_in[7];
    const float* hist_vals = (const float*)d_in[8];
    const int*   agg_rows = (const int*)d_in[9];
    const int*   agg_cols = (const int*)d_in[10];
    const float* agg_vals = (const float*)d_in[11];

    const int U = in_sizes[0] / FD;
    const int I = in_sizes[1] / FD;
    const int B = in_sizes[2] / FD;
    const int nnz_aff  = in_sizes[3];
    const int nnz_hist = in_sizes[6];
    const int nnz_agg  = in_sizes[9];
    const int n1 = U + I;   // aff graph node count
    const int n2 = U + B;   // hist graph node count

    float* out = (float*)d_out;

    // workspace: three n1*FD buffers (n1 >= n2)
    const long long buf_elems = (long long)n1 * FD;
    float* cur = (float*)d_ws;
    float* nxt = cur + buf_elems;
    float* acc = nxt + buf_elems;

    const int BLK = 256;
    const long long n1e = (long long)n1 * FD;
    const long long n2e = (long long)n2 * FD;
    const long long Ue  = (long long)U * FD;
    const long long Be  = (long long)B * FD;

    // ---------------- aff propagate over (U+I) nodes ----------------
    init_concat_kernel<<<gridFor(n1e, BLK), BLK, 0, stream>>>(
        users, Ue, items, (long long)I * FD, cur, acc);

    zero_kernel<<<gridFor(n1e, BLK), BLK, 0, stream>>>(nxt, n1e);
    spmm_scatter_kernel<<<gridFor((long long)nnz_aff * 64, BLK), BLK, 0, stream>>>(
        aff_rows, aff_cols, aff_vals, cur, nxt, nnz_aff, 0.5f);
    l2norm_acc_kernel<<<gridFor(n1e, BLK), BLK, 0, stream>>>(nxt, acc, n1);

    zero_kernel<<<gridFor(n1e, BLK), BLK, 0, stream>>>(cur, n1e);
    spmm_scatter_kernel<<<gridFor((long long)nnz_aff * 64, BLK), BLK, 0, stream>>>(
        aff_rows, aff_cols, aff_vals, nxt, cur, nnz_aff, 1.0f / 3.0f);
    l2norm_acc_kernel<<<gridFor(n1e, BLK), BLK, 0, stream>>>(cur, acc, n1);

    // aff_users -> out[0 : U*FD]
    copy_kernel<<<gridFor(Ue, BLK), BLK, 0, stream>>>(acc, out, Ue);

    // ---------------- aff_bundles = agg_spmm(aff_items) ----------------
    // out[2U*FD : (2U+B)*FD]
    float* out_aff_bundles = out + 2 * Ue;
    zero_kernel<<<gridFor(Be, BLK), BLK, 0, stream>>>(out_aff_bundles, Be);
    spmm_scatter_kernel<<<gridFor((long long)nnz_agg * 64, BLK), BLK, 0, stream>>>(
        agg_rows, agg_cols, agg_vals, acc + Ue, out_aff_bundles, nnz_agg, 1.0f);

    // ---------------- hist propagate over (U+B) nodes ----------------
    init_concat_kernel<<<gridFor(n2e, BLK), BLK, 0, stream>>>(
        users, Ue, bundles, Be, cur, acc);

    zero_kernel<<<gridFor(n2e, BLK), BLK, 0, stream>>>(nxt, n2e);
    spmm_scatter_kernel<<<gridFor((long long)nnz_hist * 64, BLK), BLK, 0, stream>>>(
        hist_rows, hist_cols, hist_vals, cur, nxt, nnz_hist, 0.5f);
    l2norm_acc_kernel<<<gridFor(n2e, BLK), BLK, 0, stream>>>(nxt, acc, n2);

    zero_kernel<<<gridFor(n2e, BLK), BLK, 0, stream>>>(cur, n2e);
    spmm_scatter_kernel<<<gridFor((long long)nnz_hist * 64, BLK), BLK, 0, stream>>>(
        hist_rows, hist_cols, hist_vals, nxt, cur, nnz_hist, 1.0f / 3.0f);
    l2norm_acc_kernel<<<gridFor(n2e, BLK), BLK, 0, stream>>>(cur, acc, n2);

    // hist_users -> out[U*FD : 2U*FD]
    copy_kernel<<<gridFor(Ue, BLK), BLK, 0, stream>>>(acc, out + Ue, Ue);
    // hist_bundles -> out[(2U+B)*FD : (2U+2B)*FD]
    copy_kernel<<<gridFor(Be, BLK), BLK, 0, stream>>>(acc + Ue, out + 2 * Ue + Be, Be);
}

// Round 2
// 1428.678 us; speedup vs baseline: 1.8480x; 1.8480x over previous
//
#include <hip/hip_runtime.h>

#define FD 64       // feature dim
#define SCAN_BLK 1024

// ---------------- small utility kernels ----------------

static __global__ void zero_int_kernel(int* __restrict__ p, int n) {
    int i = blockIdx.x * blockDim.x + threadIdx.x;
    if (i < n) p[i] = 0;
}

static __global__ void init_concat_kernel(const float* __restrict__ a, long long an,
                                          const float* __restrict__ b, long long bn,
                                          float* __restrict__ cur, float* __restrict__ acc) {
    long long i = (long long)blockIdx.x * blockDim.x + threadIdx.x;
    if (i >= an + bn) return;
    float v = (i < an) ? a[i] : b[i - an];
    cur[i] = v;
    acc[i] = v;
}

static __global__ void copy_kernel(const float* __restrict__ src, float* __restrict__ dst,
                                   long long n) {
    long long i = (long long)blockIdx.x * blockDim.x + threadIdx.x;
    if (i < n) dst[i] = src[i];
}

// ---------------- CSR build: count -> scan -> scatter ----------------

static __global__ void count_rows_kernel(const int* __restrict__ rows, int nnz,
                                         int* __restrict__ cnt) {
    int e = blockIdx.x * blockDim.x + threadIdx.x;
    if (e < nnz) atomicAdd(&cnt[rows[e]], 1);
}

// per-block total of 1024 counts
static __global__ void block_sum_kernel(const int* __restrict__ cnt, int n,
                                        int* __restrict__ psum) {
    __shared__ int sm[SCAN_BLK];
    int i = blockIdx.x * SCAN_BLK + threadIdx.x;
    sm[threadIdx.x] = (i < n) ? cnt[i] : 0;
    __syncthreads();
    for (int s = SCAN_BLK / 2; s > 0; s >>= 1) {
        if (threadIdx.x < (unsigned)s) sm[threadIdx.x] += sm[threadIdx.x + s];
        __syncthreads();
    }
    if (threadIdx.x == 0) psum[blockIdx.x] = sm[0];
}

// exclusive scan of <=1024 block sums, single block
static __global__ void scan_psum_kernel(int* __restrict__ psum, int nb) {
    __shared__ int sm[SCAN_BLK];
    int v = (threadIdx.x < (unsigned)nb) ? psum[threadIdx.x] : 0;
    sm[threadIdx.x] = v;
    __syncthreads();
    for (int off = 1; off < SCAN_BLK; off <<= 1) {
        int t = (threadIdx.x >= (unsigned)off) ? sm[threadIdx.x - off] : 0;
        __syncthreads();
        sm[threadIdx.x] += t;
        __syncthreads();
    }
    if (threadIdx.x < (unsigned)nb) psum[threadIdx.x] = sm[threadIdx.x] - v;  // exclusive
}

// per-block exclusive scan + block offset -> row_ptr, row_cur
static __global__ void scan_block_kernel(const int* __restrict__ cnt, int n, int nnz,
                                         const int* __restrict__ psum,
                                         int* __restrict__ row_ptr, int* __restrict__ row_cur) {
    __shared__ int sm[SCAN_BLK];
    int i = blockIdx.x * SCAN_BLK + threadIdx.x;
    int v = (i < n) ? cnt[i] : 0;
    sm[threadIdx.x] = v;
    __syncthreads();
    for (int off = 1; off < SCAN_BLK; off <<= 1) {
        int t = (threadIdx.x >= (unsigned)off) ? sm[threadIdx.x - off] : 0;
        __syncthreads();
        sm[threadIdx.x] += t;
        __syncthreads();
    }
    if (i < n) {
        int ex = sm[threadIdx.x] - v + psum[blockIdx.x];
        row_ptr[i] = ex;
        row_cur[i] = ex;
    }
    if (i == 0) row_ptr[n] = nnz;
}

static __global__ void scatter_edges_kernel(const int* __restrict__ rows,
                                            const int* __restrict__ cols,
                                            const float* __restrict__ vals, int nnz,
                                            int* __restrict__ row_cur,
                                            int* __restrict__ ecol, float* __restrict__ eval) {
    int e = blockIdx.x * blockDim.x + threadIdx.x;
    if (e >= nnz) return;
    int p = atomicAdd(&row_cur[rows[e]], 1);
    ecol[p] = cols[e];
    eval[p] = vals[e];
}

// ---------------- fused gather SpMM (+ optional l2norm accumulate) ----------------
// One 64-lane wave per row; lane d = feature dim d.
// s = scale * sum_e val[e] * feats[ecol[e]*64 + d]
// if WRITE_OUT: outbuf[r*64+d] = s
// if NORM:      accbuf[r*64+d] += s / max(||s_row||2, 1e-12)
template <bool WRITE_OUT, bool NORM>
static __global__ void spmm_gather_kernel(const int* __restrict__ row_ptr,
                                          const int* __restrict__ ecol,
                                          const float* __restrict__ eval,
                                          const float* __restrict__ feats,
                                          float* __restrict__ outbuf,
                                          float* __restrict__ accbuf,
                                          int n, float scale) {
    long long t = (long long)blockIdx.x * blockDim.x + threadIdx.x;
    int r = (int)(t >> 6);
    if (r >= n) return;
    int d = (int)(t & 63);
    int beg = row_ptr[r];
    int end = row_ptr[r + 1];
    float acc = 0.0f;
    int e = beg;
    for (; e + 1 < end; e += 2) {
        int c0 = ecol[e];
        int c1 = ecol[e + 1];
        float v0 = eval[e];
        float v1 = eval[e + 1];
        float f0 = feats[(long long)c0 * FD + d];
        float f1 = feats[(long long)c1 * FD + d];
        acc += v0 * f0;
        acc += v1 * f1;
    }
    if (e < end) acc += eval[e] * feats[(long long)ecol[e] * FD + d];
    float s = acc * scale;
    long long idx = (long long)r * FD + d;
    if (WRITE_OUT) outbuf[idx] = s;
    if (NORM) {
        float sq = s * s;
        #pragma unroll
        for (int off = 32; off > 0; off >>= 1) sq += __shfl_xor(sq, off);
        accbuf[idx] += s / fmaxf(sqrtf(sq), 1e-12f);
    }
}

static inline unsigned gridFor(long long n, int block) {
    return (unsigned)((n + block - 1) / block);
}

// builds CSR for (rows, cols, vals) with n segments into row_ptr/row_cur/ecol/eval
static void build_csr(const int* rows, const int* cols, const float* vals, int nnz, int n,
                      int* row_ptr, int* row_cur, int* psum, int* ecol, float* eval,
                      hipStream_t stream) {
    const int BLK = 256;
    int nb = (n + SCAN_BLK - 1) / SCAN_BLK;
    zero_int_kernel<<<gridFor(n, BLK), BLK, 0, stream>>>(row_cur, n);
    count_rows_kernel<<<gridFor(nnz, BLK), BLK, 0, stream>>>(rows, nnz, row_cur);
    block_sum_kernel<<<nb, SCAN_BLK, 0, stream>>>(row_cur, n, psum);
    scan_psum_kernel<<<1, SCAN_BLK, 0, stream>>>(psum, nb);
    scan_block_kernel<<<nb, SCAN_BLK, 0, stream>>>(row_cur, n, nnz, psum, row_ptr, row_cur);
    scatter_edges_kernel<<<gridFor(nnz, BLK), BLK, 0, stream>>>(rows, cols, vals, nnz,
                                                                row_cur, ecol, eval);
}

extern "C" void kernel_launch(void* const* d_in, const int* in_sizes, int n_in,
                              void* d_out, int out_size, void* d_ws, size_t ws_size,
                              hipStream_t stream) {
    const float* users   = (const float*)d_in[0];
    const float* items   = (const float*)d_in[1];
    const float* bundles = (const float*)d_in[2];
    const int*   aff_rows = (const int*)d_in[3];
    const int*   aff_cols = (const int*)d_in[4];
    const float* aff_vals = (const float*)d_in[5];
    const int*   hist_rows = (const int*)d_in[6];
    const int*   hist_cols = (const int*)d_in[7];
    const float* hist_vals = (const float*)d_in[8];
    const int*   agg_rows = (const int*)d_in[9];
    const int*   agg_cols = (const int*)d_in[10];
    const float* agg_vals = (const float*)d_in[11];

    const int U = in_sizes[0] / FD;
    const int I = in_sizes[1] / FD;
    const int B = in_sizes[2] / FD;
    const int nnz_aff  = in_sizes[3];
    const int nnz_hist = in_sizes[6];
    const int nnz_agg  = in_sizes[9];
    const int n1 = U + I;   // aff graph node count
    const int n2 = U + B;   // hist graph node count
    int nnz_max = nnz_aff > nnz_hist ? nnz_aff : nnz_hist;
    if (nnz_agg > nnz_max) nnz_max = nnz_agg;

    float* out = (float*)d_out;

    // workspace layout
    const long long buf_elems = (long long)n1 * FD;
    float* cur = (float*)d_ws;
    float* nxt = cur + buf_elems;
    float* acc = nxt + buf_elems;
    float* eval = acc + buf_elems;           // nnz_max floats
    int*   ecol = (int*)(eval + nnz_max);    // nnz_max ints
    int*   row_ptr = ecol + nnz_max;         // n1+1 ints
    int*   row_cur = row_ptr + (n1 + 1);     // n1 ints
    int*   psum    = row_cur + n1;           // <=1024 ints

    const int BLK = 256;
    const long long Ue  = (long long)U * FD;
    const long long Ie  = (long long)I * FD;
    const long long Be  = (long long)B * FD;
    const long long n1e = (long long)n1 * FD;
    const long long n2e = (long long)n2 * FD;

    // ---------------- aff propagate over (U+I) nodes ----------------
    build_csr(aff_rows, aff_cols, aff_vals, nnz_aff, n1,
              row_ptr, row_cur, psum, ecol, eval, stream);
    init_concat_kernel<<<gridFor(n1e, BLK), BLK, 0, stream>>>(users, Ue, items, Ie, cur, acc);
    // layer 1: nxt = spmm(cur)/2 ; acc += l2norm(nxt)
    spmm_gather_kernel<true, true><<<gridFor(n1e, BLK), BLK, 0, stream>>>(
        row_ptr, ecol, eval, cur, nxt, acc, n1, 0.5f);
    // layer 2: acc += l2norm(spmm(nxt)/3)   (output not materialized)
    spmm_gather_kernel<false, true><<<gridFor(n1e, BLK), BLK, 0, stream>>>(
        row_ptr, ecol, eval, nxt, nullptr, acc, n1, 1.0f / 3.0f);

    // aff_users -> out[0 : U*FD]
    copy_kernel<<<gridFor(Ue, BLK), BLK, 0, stream>>>(acc, out, Ue);

    // ---------------- aff_bundles = agg_spmm(aff_items) -> out[2U : 2U+B] ----------------
    build_csr(agg_rows, agg_cols, agg_vals, nnz_agg, B,
              row_ptr, row_cur, psum, ecol, eval, stream);
    spmm_gather_kernel<true, false><<<gridFor(Be, BLK), BLK, 0, stream>>>(
        row_ptr, ecol, eval, acc + Ue, out + 2 * Ue, nullptr, B, 1.0f);

    // ---------------- hist propagate over (U+B) nodes ----------------
    build_csr(hist_rows, hist_cols, hist_vals, nnz_hist, n2,
              row_ptr, row_cur, psum, ecol, eval, stream);
    init_concat_kernel<<<gridFor(n2e, BLK), BLK, 0, stream>>>(users, Ue, bundles, Be, cur, acc);
    spmm_gather_kernel<true, true><<<gridFor(n2e, BLK), BLK, 0, stream>>>(
        row_ptr, ecol, eval, cur, nxt, acc, n2, 0.5f);
    spmm_gather_kernel<false, true><<<gridFor(n2e, BLK), BLK, 0, stream>>>(
        row_ptr, ecol, eval, nxt, nullptr, acc, n2, 1.0f / 3.0f);

    // hist_users -> out[U : 2U]
    copy_kernel<<<gridFor(Ue, BLK), BLK, 0, stream>>>(acc, out + Ue, Ue);
    // hist_bundles -> out[2U+B : 2U+2B]
    copy_kernel<<<gridFor(Be, BLK), BLK, 0, stream>>>(acc + Ue, out + 2 * Ue + Be, Be);
}

// Round 3
// 1295.028 us; speedup vs baseline: 2.0388x; 1.1032x over previous
//
#include <hip/hip_runtime.h>

#define FD 64       // feature dim
#define SCAN_BLK 1024

// ---------------- small utility kernels ----------------

static __global__ void zero_int_kernel(int* __restrict__ p, int n) {
    int i = blockIdx.x * blockDim.x + threadIdx.x;
    if (i < n) p[i] = 0;
}

static __global__ void init_concat_kernel(const float* __restrict__ a, long long an,
                                          const float* __restrict__ b, long long bn,
                                          float* __restrict__ cur, float* __restrict__ acc) {
    long long i = (long long)blockIdx.x * blockDim.x + threadIdx.x;
    if (i >= an + bn) return;
    float v = (i < an) ? a[i] : b[i - an];
    cur[i] = v;
    acc[i] = v;
}

// ---------------- CSR build: count -> scan -> scatter ----------------

static __global__ void count_rows_kernel(const int* __restrict__ rows, int nnz,
                                         int* __restrict__ cnt) {
    int e = blockIdx.x * blockDim.x + threadIdx.x;
    if (e < nnz) atomicAdd(&cnt[rows[e]], 1);
}

// per-block total of SCAN_BLK counts
static __global__ void block_sum_kernel(const int* __restrict__ cnt, int n,
                                        int* __restrict__ psum) {
    __shared__ int sm[SCAN_BLK];
    int i = blockIdx.x * SCAN_BLK + threadIdx.x;
    sm[threadIdx.x] = (i < n) ? cnt[i] : 0;
    __syncthreads();
    for (int s = SCAN_BLK / 2; s > 0; s >>= 1) {
        if (threadIdx.x < (unsigned)s) sm[threadIdx.x] += sm[threadIdx.x + s];
        __syncthreads();
    }
    if (threadIdx.x == 0) psum[blockIdx.x] = sm[0];
}

// exclusive scan of <=1024 block sums, single block
static __global__ void scan_psum_kernel(int* __restrict__ psum, int nb) {
    __shared__ int sm[SCAN_BLK];
    int v = (threadIdx.x < (unsigned)nb) ? psum[threadIdx.x] : 0;
    sm[threadIdx.x] = v;
    __syncthreads();
    for (int off = 1; off < SCAN_BLK; off <<= 1) {
        int t = (threadIdx.x >= (unsigned)off) ? sm[threadIdx.x - off] : 0;
        __syncthreads();
        sm[threadIdx.x] += t;
        __syncthreads();
    }
    if (threadIdx.x < (unsigned)nb) psum[threadIdx.x] = sm[threadIdx.x] - v;  // exclusive
}

// per-block exclusive scan + block offset -> row_ptr, row_cur
static __global__ void scan_block_kernel(const int* __restrict__ cnt, int n, int nnz,
                                         const int* __restrict__ psum,
                                         int* __restrict__ row_ptr, int* __restrict__ row_cur) {
    __shared__ int sm[SCAN_BLK];
    int i = blockIdx.x * SCAN_BLK + threadIdx.x;
    int v = (i < n) ? cnt[i] : 0;
    sm[threadIdx.x] = v;
    __syncthreads();
    for (int off = 1; off < SCAN_BLK; off <<= 1) {
        int t = (threadIdx.x >= (unsigned)off) ? sm[threadIdx.x - off] : 0;
        __syncthreads();
        sm[threadIdx.x] += t;
        __syncthreads();
    }
    if (i < n) {
        int ex = sm[threadIdx.x] - v + psum[blockIdx.x];
        row_ptr[i] = ex;
        row_cur[i] = ex;
    }
    if (i == 0) row_ptr[n] = nnz;
}

// one fused 8B write per edge: (col, val) as int2
static __global__ void scatter_edges_kernel(const int* __restrict__ rows,
                                            const int* __restrict__ cols,
                                            const float* __restrict__ vals, int nnz,
                                            int* __restrict__ row_cur,
                                            int2* __restrict__ epack) {
    int e = blockIdx.x * blockDim.x + threadIdx.x;
    if (e >= nnz) return;
    int p = atomicAdd(&row_cur[rows[e]], 1);
    epack[p] = make_int2(cols[e], __float_as_int(vals[e]));
}

// ---------------- fused gather SpMM (+ optional l2norm accumulate) ----------------
// One 64-lane wave per row; lane d = feature dim d.
// s = scale * sum_e val[e] * feats[col[e]*64 + d]
// WRITE_OUT: outbuf[idx] = s    (raw spmm result)
// NORM:      res = accbuf[idx] + s / max(||s_row||2, 1e-12)
//   WRITE_ACC: accbuf[idx] = res
//   out_lo (r <  split): out_lo[r*FD+d] = res
//   out_hi (r >= split): out_hi[(r-split)*FD+d] = res
template <bool WRITE_OUT, bool NORM, bool WRITE_ACC>
static __global__ void spmm_gather_kernel(const int* __restrict__ row_ptr,
                                          const int2* __restrict__ epack,
                                          const float* __restrict__ feats,
                                          float* __restrict__ outbuf,
                                          float* __restrict__ accbuf,
                                          float* __restrict__ out_lo,
                                          float* __restrict__ out_hi,
                                          int split, int n, float scale) {
    long long t = (long long)blockIdx.x * blockDim.x + threadIdx.x;
    int r = (int)(t >> 6);
    if (r >= n) return;
    int d = (int)(t & 63);
    int beg = row_ptr[r];
    int end = row_ptr[r + 1];
    float acc = 0.0f;
    int e = beg;
    for (; e + 3 < end; e += 4) {
        int2 p0 = epack[e];
        int2 p1 = epack[e + 1];
        int2 p2 = epack[e + 2];
        int2 p3 = epack[e + 3];
        float f0 = feats[(long long)p0.x * FD + d];
        float f1 = feats[(long long)p1.x * FD + d];
        float f2 = feats[(long long)p2.x * FD + d];
        float f3 = feats[(long long)p3.x * FD + d];
        acc += __int_as_float(p0.y) * f0;
        acc += __int_as_float(p1.y) * f1;
        acc += __int_as_float(p2.y) * f2;
        acc += __int_as_float(p3.y) * f3;
    }
    for (; e < end; ++e) {
        int2 p = epack[e];
        acc += __int_as_float(p.y) * feats[(long long)p.x * FD + d];
    }
    float s = acc * scale;
    long long idx = (long long)r * FD + d;
    if (WRITE_OUT) outbuf[idx] = s;
    if (NORM) {
        float sq = s * s;
        #pragma unroll
        for (int off = 32; off > 0; off >>= 1) sq += __shfl_xor(sq, off);
        float res = accbuf[idx] + s / fmaxf(sqrtf(sq), 1e-12f);
        if (WRITE_ACC) accbuf[idx] = res;
        if (out_lo && r < split) out_lo[(long long)r * FD + d] = res;
        if (out_hi && r >= split) out_hi[(long long)(r - split) * FD + d] = res;
    }
}

static inline unsigned gridFor(long long n, int block) {
    return (unsigned)((n + block - 1) / block);
}

// builds CSR for (rows, cols, vals) with n segments into row_ptr/row_cur/epack
static void build_csr(const int* rows, const int* cols, const float* vals, int nnz, int n,
                      int* row_ptr, int* row_cur, int* psum, int2* epack,
                      hipStream_t stream) {
    const int BLK = 256;
    int nb = (n + SCAN_BLK - 1) / SCAN_BLK;
    zero_int_kernel<<<gridFor(n, BLK), BLK, 0, stream>>>(row_cur, n);
    count_rows_kernel<<<gridFor(nnz, BLK), BLK, 0, stream>>>(rows, nnz, row_cur);
    block_sum_kernel<<<nb, SCAN_BLK, 0, stream>>>(row_cur, n, psum);
    scan_psum_kernel<<<1, SCAN_BLK, 0, stream>>>(psum, nb);
    scan_block_kernel<<<nb, SCAN_BLK, 0, stream>>>(row_cur, n, nnz, psum, row_ptr, row_cur);
    scatter_edges_kernel<<<gridFor(nnz, BLK), BLK, 0, stream>>>(rows, cols, vals, nnz,
                                                                row_cur, epack);
}

extern "C" void kernel_launch(void* const* d_in, const int* in_sizes, int n_in,
                              void* d_out, int out_size, void* d_ws, size_t ws_size,
                              hipStream_t stream) {
    const float* users   = (const float*)d_in[0];
    const float* items   = (const float*)d_in[1];
    const float* bundles = (const float*)d_in[2];
    const int*   aff_rows = (const int*)d_in[3];
    const int*   aff_cols = (const int*)d_in[4];
    const float* aff_vals = (const float*)d_in[5];
    const int*   hist_rows = (const int*)d_in[6];
    const int*   hist_cols = (const int*)d_in[7];
    const float* hist_vals = (const float*)d_in[8];
    const int*   agg_rows = (const int*)d_in[9];
    const int*   agg_cols = (const int*)d_in[10];
    const float* agg_vals = (const float*)d_in[11];

    const int U = in_sizes[0] / FD;
    const int I = in_sizes[1] / FD;
    const int B = in_sizes[2] / FD;
    const int nnz_aff  = in_sizes[3];
    const int nnz_hist = in_sizes[6];
    const int nnz_agg  = in_sizes[9];
    const int n1 = U + I;   // aff graph node count
    const int n2 = U + B;   // hist graph node count
    int nnz_max = nnz_aff > nnz_hist ? nnz_aff : nnz_hist;
    if (nnz_agg > nnz_max) nnz_max = nnz_agg;

    float* out = (float*)d_out;

    // workspace layout
    const long long buf_elems = (long long)n1 * FD;
    float* cur = (float*)d_ws;
    float* nxt = cur + buf_elems;
    float* acc = nxt + buf_elems;
    int2*  epack = (int2*)(acc + buf_elems);      // nnz_max int2
    int*   row_ptr = (int*)(epack + nnz_max);     // n1+1 ints
    int*   row_cur = row_ptr + (n1 + 1);          // n1 ints
    int*   psum    = row_cur + n1;                // <=1024 ints

    const int BLK = 256;
    const long long Ue  = (long long)U * FD;
    const long long Ie  = (long long)I * FD;
    const long long Be  = (long long)B * FD;
    const long long n1e = (long long)n1 * FD;
    const long long n2e = (long long)n2 * FD;

    // ---------------- aff propagate over (U+I) nodes ----------------
    build_csr(aff_rows, aff_cols, aff_vals, nnz_aff, n1,
              row_ptr, row_cur, psum, epack, stream);
    init_concat_kernel<<<gridFor(n1e, BLK), BLK, 0, stream>>>(users, Ue, items, Ie, cur, acc);
    // layer 1: nxt = spmm(cur)/2 ; acc += l2norm(nxt)
    spmm_gather_kernel<true, true, true><<<gridFor(n1e, BLK), BLK, 0, stream>>>(
        row_ptr, epack, cur, nxt, acc, nullptr, nullptr, 0, n1, 0.5f);
    // layer 2: acc += l2norm(spmm(nxt)/3); rows<U also -> out (aff_users)
    spmm_gather_kernel<false, true, true><<<gridFor(n1e, BLK), BLK, 0, stream>>>(
        row_ptr, epack, nxt, nullptr, acc, out, nullptr, U, n1, 1.0f / 3.0f);

    // ---------------- aff_bundles = agg_spmm(aff_items) -> out[2U : 2U+B] ----------------
    build_csr(agg_rows, agg_cols, agg_vals, nnz_agg, B,
              row_ptr, row_cur, psum, epack, stream);
    spmm_gather_kernel<true, false, false><<<gridFor(Be, BLK), BLK, 0, stream>>>(
        row_ptr, epack, acc + Ue, out + 2 * Ue, nullptr, nullptr, nullptr, 0, B, 1.0f);

    // ---------------- hist propagate over (U+B) nodes ----------------
    build_csr(hist_rows, hist_cols, hist_vals, nnz_hist, n2,
              row_ptr, row_cur, psum, epack, stream);
    init_concat_kernel<<<gridFor(n2e, BLK), BLK, 0, stream>>>(users, Ue, bundles, Be, cur, acc);
    spmm_gather_kernel<true, true, true><<<gridFor(n2e, BLK), BLK, 0, stream>>>(
        row_ptr, epack, cur, nxt, acc, nullptr, nullptr, 0, n2, 0.5f);
    // layer 2: res = acc + l2norm(spmm/3); rows<U -> hist_users, rows>=U -> hist_bundles
    spmm_gather_kernel<false, true, false><<<gridFor(n2e, BLK), BLK, 0, stream>>>(
        row_ptr, epack, nxt, nullptr, acc, out + Ue, out + 2 * Ue + Be, U, n2, 1.0f / 3.0f);
}